// Round 3
// baseline (682.084 us; speedup 1.0000x reference)
//
#include <hip/hip_runtime.h>

#define HP 192
#define WP 192
#define NPIX (HP * WP)   // 36864
#define SG 24
#define KSTR 68          // smKV row stride (floats): 272 B, 16B-aligned
#define PSTR 12          // smpi row stride (floats)

// ---------------- Kernel 1: QKV projection -----------------------------------
__global__ __launch_bounds__(256) void qkv_kernel(
    const float* __restrict__ x,
    const float* __restrict__ w_qk,
    const float* __restrict__ w_v,
    float* __restrict__ qb, float* __restrict__ kb, float* __restrict__ vb) {
  const int jb = blockIdx.y;  // 0..5
  const int pix = blockIdx.x * 256 + threadIdx.x;
  float xv[64];
#pragma unroll
  for (int c = 0; c < 64; ++c) xv[c] = x[c * NPIX + pix];
  float acc[32];
#pragma unroll
  for (int j = 0; j < 32; ++j) acc[j] = 0.f;
  const int j0 = jb * 32;
  if (jb < 4) {
#pragma unroll
    for (int c = 0; c < 64; ++c) {
      const float* wr = w_qk + c * 128 + j0;
      const float xc = xv[c];
#pragma unroll
      for (int j = 0; j < 32; ++j) acc[j] = fmaf(xc, wr[j], acc[j]);
    }
  } else {
#pragma unroll
    for (int c = 0; c < 64; ++c) {
      const float* wr = w_v + c * 64 + (j0 - 128);
      const float xc = xv[c];
#pragma unroll
      for (int j = 0; j < 32; ++j) acc[j] = fmaf(xc, wr[j], acc[j]);
    }
  }
  float* dst;
  float mul = 1.0f;
  if (jb < 2) {
    dst = qb + (size_t)pix * 64 + j0;
    mul = 0.25f;  // hd^-0.5, hd=16
  } else if (jb < 4) {
    dst = kb + (size_t)pix * 64 + (j0 - 64);
  } else {
    dst = vb + (size_t)pix * 64 + (j0 - 128);
  }
#pragma unroll
  for (int j = 0; j < 32; ++j) dst[j] = acc[j] * mul;
}

// ---------------- Kernel 2: attention ----------------------------------------
// Block = 8x8 pixel tile, 256 threads = 64 px x 4 heads.
// One LDS buffer [196 x 68] holds the K tile for pass 1, then is REUSED for
// the V tile in pass 2 (barrier-separated). pi table [196 x 12] in LDS.
// Softmax without max-subtraction (logits bounded ~|2|): pass 1 fuses
// logit -> exp -> {S, D9} accumulation; e[] kept in 49 VGPRs.
__global__ __launch_bounds__(256) void attn_kernel(
    const float* __restrict__ qb, const float* __restrict__ kb,
    const float* __restrict__ vb, const float* __restrict__ sims,
    float* __restrict__ pre) {
  __shared__ __align__(16) float smKV[196 * KSTR];
  __shared__ __align__(16) float smpi[196 * PSTR];
  const int tile = blockIdx.x;
  const int th = tile / 24, tw = tile % 24;
  const int rowBase = th * 8 - 3, colBase = tw * 8 - 3;
  const int tid = threadIdx.x;

  // ---- stage K tile (coalesced float4) ----
  for (int i = tid; i < 196 * 16; i += 256) {
    const int loc = i >> 4, d4 = i & 15;
    const int rl = loc / 14, cl = loc - rl * 14;
    const int r = rowBase + rl, c = colBase + cl;
    float4 val = make_float4(0.f, 0.f, 0.f, 0.f);
    if (r >= 0 && r < HP && c >= 0 && c < WP)
      val = *(const float4*)(kb + ((size_t)(r * WP + c)) * 64 + (d4 << 2));
    *(float4*)(smKV + loc * KSTR + (d4 << 2)) = val;
  }
  // ---- stage pi table: 196 locations x 9 block-uniform labels ----
  for (int i = tid; i < 196 * 9; i += 256) {
    const int loc = i / 9, s = i - loc * 9;
    const int rl = loc / 14, cl = loc - rl * 14;
    const int r = rowBase + rl, c = colBase + cl;
    const int dh = s / 3, dw = s - dh * 3;
    const int shi = th + dh - 1, swj = tw + dw - 1;
    float val = 0.f;
    if (shi >= 0 && shi < SG && swj >= 0 && swj < SG && r >= 0 && r < HP &&
        c >= 0 && c < WP)
      val = sims[((size_t)(r * WP + c)) * (SG * SG) + shi * SG + swj];
    smpi[loc * PSTR + s] = val;
  }
  __syncthreads();

  const int head = tid & 3;
  const int pl = tid >> 2;
  const int py = pl >> 3, px = pl & 7;
  const int h = th * 8 + py, w = tw * 8 + px;
  const int pix = h * WP + w;
  int hs = h - 3;
  hs = hs < 0 ? 0 : (hs > HP - 7 ? HP - 7 : hs);
  int wsb = w - 3;
  wsb = wsb < 0 ? 0 : (wsb > WP - 7 ? WP - 7 : wsb);
  const int rl0 = hs - rowBase;   // 0..7
  const int cl0 = wsb - colBase;  // 0..7
  const int hq = head << 4;       // head channel base (floats)

  const float4* qp = (const float4*)(qb + (size_t)pix * 64 + hq);
  const float4 q0 = qp[0], q1 = qp[1], q2 = qp[2], q3 = qp[3];

  // ---- pass 1: logits -> exp -> S, D9 (single fused loop) ----
  float a[49];
  float D9[9];
#pragma unroll
  for (int s = 0; s < 9; ++s) D9[s] = 0.f;
  float S = 0.f;
#pragma unroll
  for (int kh = 0; kh < 7; ++kh) {
    const float* kr = smKV + ((rl0 + kh) * 14 + cl0) * KSTR + hq;
    const float* pr = smpi + ((rl0 + kh) * 14 + cl0) * PSTR;
#pragma unroll
    for (int kw = 0; kw < 7; ++kw) {
      const float* kp = kr + kw * KSTR;
      const float4 k0 = *(const float4*)(kp);
      const float4 k1 = *(const float4*)(kp + 4);
      const float4 k2 = *(const float4*)(kp + 8);
      const float4 k3 = *(const float4*)(kp + 12);
      float t = q0.x * k0.x + q0.y * k0.y + q0.z * k0.z + q0.w * k0.w;
      t += q1.x * k1.x + q1.y * k1.y + q1.z * k1.z + q1.w * k1.w;
      t += q2.x * k2.x + q2.y * k2.y + q2.z * k2.z + q2.w * k2.w;
      t += q3.x * k3.x + q3.y * k3.y + q3.z * k3.z + q3.w * k3.w;
      const float e = __expf(t);
      a[kh * 7 + kw] = e;
      S += e;
      const float* pp = pr + kw * PSTR;
      const float4 p0 = *(const float4*)pp;
      const float4 p1 = *(const float4*)(pp + 4);
      const float p8 = pp[8];
      D9[0] = fmaf(e, p0.x, D9[0]);
      D9[1] = fmaf(e, p0.y, D9[1]);
      D9[2] = fmaf(e, p0.z, D9[2]);
      D9[3] = fmaf(e, p0.w, D9[3]);
      D9[4] = fmaf(e, p1.x, D9[4]);
      D9[5] = fmaf(e, p1.y, D9[5]);
      D9[6] = fmaf(e, p1.z, D9[6]);
      D9[7] = fmaf(e, p1.w, D9[7]);
      D9[8] = fmaf(e, p8, D9[8]);
    }
  }

  // ---- coef_s = ws[s] / (D[s] + 1e-10*S) ----
  float coef[9];
  {
    const float* pp = smpi + ((h - rowBase) * 14 + (w - colBase)) * PSTR;
    const float4 p0 = *(const float4*)pp;
    const float4 p1 = *(const float4*)(pp + 4);
    const float p8 = pp[8];
    const float epsS = 1e-10f * S;
    coef[0] = p0.x / (D9[0] + epsS);
    coef[1] = p0.y / (D9[1] + epsS);
    coef[2] = p0.z / (D9[2] + epsS);
    coef[3] = p0.w / (D9[3] + epsS);
    coef[4] = p1.x / (D9[4] + epsS);
    coef[5] = p1.y / (D9[5] + epsS);
    coef[6] = p1.z / (D9[6] + epsS);
    coef[7] = p1.w / (D9[7] + epsS);
    coef[8] = p8 / (D9[8] + epsS);
  }

  // ---- swap LDS buffer: K -> V ----
  __syncthreads();  // everyone done reading K
  for (int i = tid; i < 196 * 16; i += 256) {
    const int loc = i >> 4, d4 = i & 15;
    const int rl = loc / 14, cl = loc - rl * 14;
    const int r = rowBase + rl, c = colBase + cl;
    float4 val = make_float4(0.f, 0.f, 0.f, 0.f);
    if (r >= 0 && r < HP && c >= 0 && c < WP)
      val = *(const float4*)(vb + ((size_t)(r * WP + c)) * 64 + (d4 << 2));
    *(float4*)(smKV + loc * KSTR + (d4 << 2)) = val;
  }
  __syncthreads();

  // ---- pass 2: a2 = e * (coef . pi);  o += a2 * v (LDS) ----
  float4 o0 = make_float4(0.f, 0.f, 0.f, 0.f);
  float4 o1 = make_float4(0.f, 0.f, 0.f, 0.f);
  float4 o2 = make_float4(0.f, 0.f, 0.f, 0.f);
  float4 o3 = make_float4(0.f, 0.f, 0.f, 0.f);
#pragma unroll
  for (int kh = 0; kh < 7; ++kh) {
    const float* vr = smKV + ((rl0 + kh) * 14 + cl0) * KSTR + hq;
    const float* pr = smpi + ((rl0 + kh) * 14 + cl0) * PSTR;
#pragma unroll
    for (int kw = 0; kw < 7; ++kw) {
      const float* pp = pr + kw * PSTR;
      const float4 p0 = *(const float4*)pp;
      const float4 p1 = *(const float4*)(pp + 4);
      const float p8 = pp[8];
      float t = coef[0] * p0.x + coef[1] * p0.y + coef[2] * p0.z +
                coef[3] * p0.w + coef[4] * p1.x + coef[5] * p1.y +
                coef[6] * p1.z + coef[7] * p1.w + coef[8] * p8;
      const float a2 = a[kh * 7 + kw] * t;
      const float* vp = vr + kw * KSTR;
      const float4 v0 = *(const float4*)(vp);
      const float4 v1 = *(const float4*)(vp + 4);
      const float4 v2 = *(const float4*)(vp + 8);
      const float4 v3 = *(const float4*)(vp + 12);
      o0.x = fmaf(a2, v0.x, o0.x);
      o0.y = fmaf(a2, v0.y, o0.y);
      o0.z = fmaf(a2, v0.z, o0.z);
      o0.w = fmaf(a2, v0.w, o0.w);
      o1.x = fmaf(a2, v1.x, o1.x);
      o1.y = fmaf(a2, v1.y, o1.y);
      o1.z = fmaf(a2, v1.z, o1.z);
      o1.w = fmaf(a2, v1.w, o1.w);
      o2.x = fmaf(a2, v2.x, o2.x);
      o2.y = fmaf(a2, v2.y, o2.y);
      o2.z = fmaf(a2, v2.z, o2.z);
      o2.w = fmaf(a2, v2.w, o2.w);
      o3.x = fmaf(a2, v3.x, o3.x);
      o3.y = fmaf(a2, v3.y, o3.y);
      o3.z = fmaf(a2, v3.z, o3.z);
      o3.w = fmaf(a2, v3.w, o3.w);
    }
  }
  float4* op = (float4*)(pre + (size_t)pix * 64 + hq);
  op[0] = o0;
  op[1] = o1;
  op[2] = o2;
  op[3] = o3;
}

// ---------------- Kernel 3: output projection --------------------------------
__global__ __launch_bounds__(256) void proj_kernel(
    const float* __restrict__ pre, const float* __restrict__ w_proj,
    float* __restrict__ out) {
  const int jb = blockIdx.y;  // 0..1
  const int pix = blockIdx.x * 256 + threadIdx.x;
  float xv[64];
  const float4* pp = (const float4*)(pre + (size_t)pix * 64);
#pragma unroll
  for (int i = 0; i < 16; ++i) {
    const float4 t = pp[i];
    xv[i * 4 + 0] = t.x;
    xv[i * 4 + 1] = t.y;
    xv[i * 4 + 2] = t.z;
    xv[i * 4 + 3] = t.w;
  }
  float acc[32];
#pragma unroll
  for (int j = 0; j < 32; ++j) acc[j] = 0.f;
  const int j0 = jb * 32;
#pragma unroll
  for (int c = 0; c < 64; ++c) {
    const float* wr = w_proj + c * 64 + j0;
    const float xc = xv[c];
#pragma unroll
    for (int j = 0; j < 32; ++j) acc[j] = fmaf(xc, wr[j], acc[j]);
  }
#pragma unroll
  for (int j = 0; j < 32; ++j) out[(size_t)(j0 + j) * NPIX + pix] = acc[j];
}

extern "C" void kernel_launch(void* const* d_in, const int* in_sizes, int n_in,
                              void* d_out, int out_size, void* d_ws,
                              size_t ws_size, hipStream_t stream) {
  const float* x = (const float*)d_in[0];
  const float* sims = (const float*)d_in[1];
  const float* w_qk = (const float*)d_in[2];
  const float* w_v = (const float*)d_in[3];
  const float* w_proj = (const float*)d_in[4];
  float* out = (float*)d_out;

  float* qb = (float*)d_ws;
  float* kb = qb + (size_t)NPIX * 64;
  float* vb = kb + (size_t)NPIX * 64;
  float* pre = vb + (size_t)NPIX * 64;

  qkv_kernel<<<dim3(144, 6), 256, 0, stream>>>(x, w_qk, w_v, qb, kb, vb);
  attn_kernel<<<dim3(576), 256, 0, stream>>>(qb, kb, vb, sims, pre);
  proj_kernel<<<dim3(144, 2), 256, 0, stream>>>(pre, w_proj, out);
}

// Round 4
// 153.310 us; speedup vs baseline: 4.4490x; 4.4490x over previous
//
#include <hip/hip_runtime.h>

#define HP 192
#define WP 192
#define NPIX (HP * WP)   // 36864
#define SG 24
#define KSTR 68          // smK/smV row stride (floats): 272 B, 16B-aligned
#define PSTR 12          // smpi row stride (floats)

// ---------------- Kernel 1: QKV projection -----------------------------------
__global__ __launch_bounds__(256) void qkv_kernel(
    const float* __restrict__ x,
    const float* __restrict__ w_qk,
    const float* __restrict__ w_v,
    float* __restrict__ qb, float* __restrict__ kb, float* __restrict__ vb) {
  const int jb = blockIdx.y;  // 0..5
  const int pix = blockIdx.x * 256 + threadIdx.x;
  float xv[64];
#pragma unroll
  for (int c = 0; c < 64; ++c) xv[c] = x[c * NPIX + pix];
  float acc[32];
#pragma unroll
  for (int j = 0; j < 32; ++j) acc[j] = 0.f;
  const int j0 = jb * 32;
  if (jb < 4) {
#pragma unroll
    for (int c = 0; c < 64; ++c) {
      const float* wr = w_qk + c * 128 + j0;
      const float xc = xv[c];
#pragma unroll
      for (int j = 0; j < 32; ++j) acc[j] = fmaf(xc, wr[j], acc[j]);
    }
  } else {
#pragma unroll
    for (int c = 0; c < 64; ++c) {
      const float* wr = w_v + c * 64 + (j0 - 128);
      const float xc = xv[c];
#pragma unroll
      for (int j = 0; j < 32; ++j) acc[j] = fmaf(xc, wr[j], acc[j]);
    }
  }
  float* dst;
  float mul = 1.0f;
  if (jb < 2) {
    dst = qb + (size_t)pix * 64 + j0;
    mul = 0.25f;  // hd^-0.5, hd=16
  } else if (jb < 4) {
    dst = kb + (size_t)pix * 64 + (j0 - 64);
  } else {
    dst = vb + (size_t)pix * 64 + (j0 - 128);
  }
#pragma unroll
  for (int j = 0; j < 32; ++j) dst[j] = acc[j] * mul;
}

// ---------------- Kernel 2: attention ----------------------------------------
// Block = 8x8 pixel tile, 256 threads = 64 px x 4 heads.
// K, V and pi all staged in LDS up front (113 KB, 1 block/CU), ONE barrier.
// No per-thread a[49]: pass 2 recomputes the logit/exp from the same LDS K
// (bit-identical), keeping live state ~90 VGPRs -> no spills by construction.
// Outer kh loops are NOT unrolled (runtime kh is fine: no indexed arrays).
__global__ __launch_bounds__(256) void attn_kernel(
    const float* __restrict__ qb, const float* __restrict__ kb,
    const float* __restrict__ vb, const float* __restrict__ sims,
    float* __restrict__ pre) {
  __shared__ __align__(16) float smK[196 * KSTR];
  __shared__ __align__(16) float smV[196 * KSTR];
  __shared__ __align__(16) float smpi[196 * PSTR];
  const int tile = blockIdx.x;
  const int th = tile / 24, tw = tile % 24;
  const int rowBase = th * 8 - 3, colBase = tw * 8 - 3;
  const int tid = threadIdx.x;

  // ---- stage K and V tiles (coalesced float4) ----
  for (int i = tid; i < 196 * 16; i += 256) {
    const int loc = i >> 4, d4 = i & 15;
    const int rl = loc / 14, cl = loc - rl * 14;
    const int r = rowBase + rl, c = colBase + cl;
    float4 kval = make_float4(0.f, 0.f, 0.f, 0.f);
    float4 vval = make_float4(0.f, 0.f, 0.f, 0.f);
    if (r >= 0 && r < HP && c >= 0 && c < WP) {
      const size_t base = ((size_t)(r * WP + c)) * 64 + (d4 << 2);
      kval = *(const float4*)(kb + base);
      vval = *(const float4*)(vb + base);
    }
    *(float4*)(smK + loc * KSTR + (d4 << 2)) = kval;
    *(float4*)(smV + loc * KSTR + (d4 << 2)) = vval;
  }
  // ---- stage pi table: 196 locations x 9 block-uniform labels ----
  for (int i = tid; i < 196 * 9; i += 256) {
    const int loc = i / 9, s = i - loc * 9;
    const int rl = loc / 14, cl = loc - rl * 14;
    const int r = rowBase + rl, c = colBase + cl;
    const int dh = s / 3, dw = s - dh * 3;
    const int shi = th + dh - 1, swj = tw + dw - 1;
    float val = 0.f;
    if (shi >= 0 && shi < SG && swj >= 0 && swj < SG && r >= 0 && r < HP &&
        c >= 0 && c < WP)
      val = sims[((size_t)(r * WP + c)) * (SG * SG) + shi * SG + swj];
    smpi[loc * PSTR + s] = val;
  }
  __syncthreads();

  const int head = tid & 3;
  const int pl = tid >> 2;
  const int py = pl >> 3, px = pl & 7;
  const int h = th * 8 + py, w = tw * 8 + px;
  const int pix = h * WP + w;
  int hs = h - 3;
  hs = hs < 0 ? 0 : (hs > HP - 7 ? HP - 7 : hs);
  int wsb = w - 3;
  wsb = wsb < 0 ? 0 : (wsb > WP - 7 ? WP - 7 : wsb);
  const int rl0 = hs - rowBase;   // 0..7
  const int cl0 = wsb - colBase;  // 0..7
  const int hq = head << 4;       // head channel base (floats)

  const float4* qp = (const float4*)(qb + (size_t)pix * 64 + hq);
  const float4 q0 = qp[0], q1 = qp[1], q2 = qp[2], q3 = qp[3];

  // ---- pass 1: logits -> exp -> S, D9 (no per-neighbor storage) ----
  float D9[9];
#pragma unroll
  for (int s = 0; s < 9; ++s) D9[s] = 0.f;
  float S = 0.f;
#pragma unroll 1
  for (int kh = 0; kh < 7; ++kh) {
    const int rbase = (rl0 + kh) * 14 + cl0;
    const float* kr = smK + rbase * KSTR + hq;
    const float* pr = smpi + rbase * PSTR;
#pragma unroll
    for (int kw = 0; kw < 7; ++kw) {
      const float* kp = kr + kw * KSTR;
      const float4 k0 = *(const float4*)(kp);
      const float4 k1 = *(const float4*)(kp + 4);
      const float4 k2 = *(const float4*)(kp + 8);
      const float4 k3 = *(const float4*)(kp + 12);
      float t = q0.x * k0.x + q0.y * k0.y + q0.z * k0.z + q0.w * k0.w;
      t += q1.x * k1.x + q1.y * k1.y + q1.z * k1.z + q1.w * k1.w;
      t += q2.x * k2.x + q2.y * k2.y + q2.z * k2.z + q2.w * k2.w;
      t += q3.x * k3.x + q3.y * k3.y + q3.z * k3.z + q3.w * k3.w;
      const float e = __expf(t);
      S += e;
      const float* pp = pr + kw * PSTR;
      const float4 p0 = *(const float4*)pp;
      const float4 p1 = *(const float4*)(pp + 4);
      const float p8 = pp[8];
      D9[0] = fmaf(e, p0.x, D9[0]);
      D9[1] = fmaf(e, p0.y, D9[1]);
      D9[2] = fmaf(e, p0.z, D9[2]);
      D9[3] = fmaf(e, p0.w, D9[3]);
      D9[4] = fmaf(e, p1.x, D9[4]);
      D9[5] = fmaf(e, p1.y, D9[5]);
      D9[6] = fmaf(e, p1.z, D9[6]);
      D9[7] = fmaf(e, p1.w, D9[7]);
      D9[8] = fmaf(e, p8, D9[8]);
    }
  }

  // ---- coef_s = ws[s] / (D[s] + 1e-10*S) ----
  float coef[9];
  {
    const float* pp = smpi + ((h - rowBase) * 14 + (w - colBase)) * PSTR;
    const float4 p0 = *(const float4*)pp;
    const float4 p1 = *(const float4*)(pp + 4);
    const float p8 = pp[8];
    const float epsS = 1e-10f * S;
    coef[0] = p0.x / (D9[0] + epsS);
    coef[1] = p0.y / (D9[1] + epsS);
    coef[2] = p0.z / (D9[2] + epsS);
    coef[3] = p0.w / (D9[3] + epsS);
    coef[4] = p1.x / (D9[4] + epsS);
    coef[5] = p1.y / (D9[5] + epsS);
    coef[6] = p1.z / (D9[6] + epsS);
    coef[7] = p1.w / (D9[7] + epsS);
    coef[8] = p8 / (D9[8] + epsS);
  }

  // ---- pass 2: recompute e; a2 = e * (coef . pi); o += a2 * v (LDS) ----
  float4 o0 = make_float4(0.f, 0.f, 0.f, 0.f);
  float4 o1 = make_float4(0.f, 0.f, 0.f, 0.f);
  float4 o2 = make_float4(0.f, 0.f, 0.f, 0.f);
  float4 o3 = make_float4(0.f, 0.f, 0.f, 0.f);
#pragma unroll 1
  for (int kh = 0; kh < 7; ++kh) {
    const int rbase = (rl0 + kh) * 14 + cl0;
    const float* kr = smK + rbase * KSTR + hq;
    const float* vr = smV + rbase * KSTR + hq;
    const float* pr = smpi + rbase * PSTR;
#pragma unroll
    for (int kw = 0; kw < 7; ++kw) {
      const float* kp = kr + kw * KSTR;
      const float4 k0 = *(const float4*)(kp);
      const float4 k1 = *(const float4*)(kp + 4);
      const float4 k2 = *(const float4*)(kp + 8);
      const float4 k3 = *(const float4*)(kp + 12);
      float t = q0.x * k0.x + q0.y * k0.y + q0.z * k0.z + q0.w * k0.w;
      t += q1.x * k1.x + q1.y * k1.y + q1.z * k1.z + q1.w * k1.w;
      t += q2.x * k2.x + q2.y * k2.y + q2.z * k2.z + q2.w * k2.w;
      t += q3.x * k3.x + q3.y * k3.y + q3.z * k3.z + q3.w * k3.w;
      const float e = __expf(t);
      const float* pp = pr + kw * PSTR;
      const float4 p0 = *(const float4*)pp;
      const float4 p1 = *(const float4*)(pp + 4);
      const float p8 = pp[8];
      float tc = coef[0] * p0.x + coef[1] * p0.y + coef[2] * p0.z +
                 coef[3] * p0.w + coef[4] * p1.x + coef[5] * p1.y +
                 coef[6] * p1.z + coef[7] * p1.w + coef[8] * p8;
      const float a2 = e * tc;
      const float* vp = vr + kw * KSTR;
      const float4 v0 = *(const float4*)(vp);
      const float4 v1 = *(const float4*)(vp + 4);
      const float4 v2 = *(const float4*)(vp + 8);
      const float4 v3 = *(const float4*)(vp + 12);
      o0.x = fmaf(a2, v0.x, o0.x);
      o0.y = fmaf(a2, v0.y, o0.y);
      o0.z = fmaf(a2, v0.z, o0.z);
      o0.w = fmaf(a2, v0.w, o0.w);
      o1.x = fmaf(a2, v1.x, o1.x);
      o1.y = fmaf(a2, v1.y, o1.y);
      o1.z = fmaf(a2, v1.z, o1.z);
      o1.w = fmaf(a2, v1.w, o1.w);
      o2.x = fmaf(a2, v2.x, o2.x);
      o2.y = fmaf(a2, v2.y, o2.y);
      o2.z = fmaf(a2, v2.z, o2.z);
      o2.w = fmaf(a2, v2.w, o2.w);
      o3.x = fmaf(a2, v3.x, o3.x);
      o3.y = fmaf(a2, v3.y, o3.y);
      o3.z = fmaf(a2, v3.z, o3.z);
      o3.w = fmaf(a2, v3.w, o3.w);
    }
  }
  float4* op = (float4*)(pre + (size_t)pix * 64 + hq);
  op[0] = o0;
  op[1] = o1;
  op[2] = o2;
  op[3] = o3;
}

// ---------------- Kernel 3: output projection --------------------------------
__global__ __launch_bounds__(256) void proj_kernel(
    const float* __restrict__ pre, const float* __restrict__ w_proj,
    float* __restrict__ out) {
  const int jb = blockIdx.y;  // 0..1
  const int pix = blockIdx.x * 256 + threadIdx.x;
  float xv[64];
  const float4* pp = (const float4*)(pre + (size_t)pix * 64);
#pragma unroll
  for (int i = 0; i < 16; ++i) {
    const float4 t = pp[i];
    xv[i * 4 + 0] = t.x;
    xv[i * 4 + 1] = t.y;
    xv[i * 4 + 2] = t.z;
    xv[i * 4 + 3] = t.w;
  }
  float acc[32];
#pragma unroll
  for (int j = 0; j < 32; ++j) acc[j] = 0.f;
  const int j0 = jb * 32;
#pragma unroll
  for (int c = 0; c < 64; ++c) {
    const float* wr = w_proj + c * 64 + j0;
    const float xc = xv[c];
#pragma unroll
    for (int j = 0; j < 32; ++j) acc[j] = fmaf(xc, wr[j], acc[j]);
  }
#pragma unroll
  for (int j = 0; j < 32; ++j) out[(size_t)(j0 + j) * NPIX + pix] = acc[j];
}

extern "C" void kernel_launch(void* const* d_in, const int* in_sizes, int n_in,
                              void* d_out, int out_size, void* d_ws,
                              size_t ws_size, hipStream_t stream) {
  const float* x = (const float*)d_in[0];
  const float* sims = (const float*)d_in[1];
  const float* w_qk = (const float*)d_in[2];
  const float* w_v = (const float*)d_in[3];
  const float* w_proj = (const float*)d_in[4];
  float* out = (float*)d_out;

  float* qb = (float*)d_ws;
  float* kb = qb + (size_t)NPIX * 64;
  float* vb = kb + (size_t)NPIX * 64;
  float* pre = vb + (size_t)NPIX * 64;

  qkv_kernel<<<dim3(144, 6), 256, 0, stream>>>(x, w_qk, w_v, qb, kb, vb);
  attn_kernel<<<dim3(576), 256, 0, stream>>>(qb, kb, vb, sims, pre);
  proj_kernel<<<dim3(144, 2), 256, 0, stream>>>(pre, w_proj, out);
}

// Round 5
// 123.842 us; speedup vs baseline: 5.5077x; 1.2379x over previous
//
#include <hip/hip_runtime.h>

#define HP 192
#define WP 192
#define NPIX (HP * WP)   // 36864
#define SG 24
#define KSTRU 72         // smK/smV row stride in ushorts: 144 B, 16B-aligned
#define PSTR 12          // smpi row stride (floats)

__device__ __forceinline__ unsigned int bfpack(float a, float b) {
  unsigned int ua = __float_as_uint(a), ub = __float_as_uint(b);
  ua = (ua + 0x7FFFu + ((ua >> 16) & 1u)) >> 16;   // RTNE bf16
  ub = (ub + 0x7FFFu + ((ub >> 16) & 1u)) >> 16;
  return ua | (ub << 16);
}

// ---------------- Kernel 1: QKV projection -----------------------------------
__global__ __launch_bounds__(256) void qkv_kernel(
    const float* __restrict__ x,
    const float* __restrict__ w_qk,
    const float* __restrict__ w_v,
    float* __restrict__ qb, float* __restrict__ kb, float* __restrict__ vb) {
  const int jb = blockIdx.y;  // 0..5
  const int pix = blockIdx.x * 256 + threadIdx.x;
  float xv[64];
#pragma unroll
  for (int c = 0; c < 64; ++c) xv[c] = x[c * NPIX + pix];
  float acc[32];
#pragma unroll
  for (int j = 0; j < 32; ++j) acc[j] = 0.f;
  const int j0 = jb * 32;
  if (jb < 4) {
#pragma unroll
    for (int c = 0; c < 64; ++c) {
      const float* wr = w_qk + c * 128 + j0;
      const float xc = xv[c];
#pragma unroll
      for (int j = 0; j < 32; ++j) acc[j] = fmaf(xc, wr[j], acc[j]);
    }
  } else {
#pragma unroll
    for (int c = 0; c < 64; ++c) {
      const float* wr = w_v + c * 64 + (j0 - 128);
      const float xc = xv[c];
#pragma unroll
      for (int j = 0; j < 32; ++j) acc[j] = fmaf(xc, wr[j], acc[j]);
    }
  }
  float* dst;
  float mul = 1.0f;
  if (jb < 2) {
    dst = qb + (size_t)pix * 64 + j0;
    mul = 0.25f;  // hd^-0.5, hd=16
  } else if (jb < 4) {
    dst = kb + (size_t)pix * 64 + (j0 - 64);
  } else {
    dst = vb + (size_t)pix * 64 + (j0 - 128);
  }
#pragma unroll
  for (int j = 0; j < 32; ++j) dst[j] = acc[j] * mul;
}

// ---------------- Kernel 2: attention ----------------------------------------
// Block = 8x8 pixel tile, 256 threads = 64 px x 4 heads.
// K and V staged in LDS as bf16 (RTNE): 2x28.2 KB + 9.4 KB pi = 66 KB ->
// 2 blocks/CU (8 waves, 2/SIMD) and half the ds_read_b128 count vs f32.
// No per-thread a[49]: pass 2 recomputes exp from the same LDS bf16 K.
__global__ __launch_bounds__(256) void attn_kernel(
    const float* __restrict__ qb, const float* __restrict__ kb,
    const float* __restrict__ vb, const float* __restrict__ sims,
    float* __restrict__ pre) {
  __shared__ __align__(16) unsigned short smK[196 * KSTRU];
  __shared__ __align__(16) unsigned short smV[196 * KSTRU];
  __shared__ __align__(16) float smpi[196 * PSTR];
  const int tile = blockIdx.x;
  const int th = tile / 24, tw = tile % 24;
  const int rowBase = th * 8 - 3, colBase = tw * 8 - 3;
  const int tid = threadIdx.x;

  // ---- stage K and V tiles: global f32 -> bf16 LDS (8-ch chunks) ----
  for (int i = tid; i < 196 * 8; i += 256) {
    const int loc = i >> 3, d8 = i & 7;
    const int rl = loc / 14, cl = loc - rl * 14;
    const int r = rowBase + rl, c = colBase + cl;
    uint4 kw4 = make_uint4(0u, 0u, 0u, 0u);
    uint4 vw4 = make_uint4(0u, 0u, 0u, 0u);
    if (r >= 0 && r < HP && c >= 0 && c < WP) {
      const size_t base = ((size_t)(r * WP + c)) * 64 + (d8 << 3);
      const float4 ka = *(const float4*)(kb + base);
      const float4 kb8 = *(const float4*)(kb + base + 4);
      const float4 va = *(const float4*)(vb + base);
      const float4 vb8 = *(const float4*)(vb + base + 4);
      kw4.x = bfpack(ka.x, ka.y);
      kw4.y = bfpack(ka.z, ka.w);
      kw4.z = bfpack(kb8.x, kb8.y);
      kw4.w = bfpack(kb8.z, kb8.w);
      vw4.x = bfpack(va.x, va.y);
      vw4.y = bfpack(va.z, va.w);
      vw4.z = bfpack(vb8.x, vb8.y);
      vw4.w = bfpack(vb8.z, vb8.w);
    }
    *(uint4*)(smK + loc * KSTRU + (d8 << 3)) = kw4;
    *(uint4*)(smV + loc * KSTRU + (d8 << 3)) = vw4;
  }
  // ---- stage pi table: 196 locations x 9 block-uniform labels (f32) ----
  for (int i = tid; i < 196 * 9; i += 256) {
    const int loc = i / 9, s = i - loc * 9;
    const int rl = loc / 14, cl = loc - rl * 14;
    const int r = rowBase + rl, c = colBase + cl;
    const int dh = s / 3, dw = s - dh * 3;
    const int shi = th + dh - 1, swj = tw + dw - 1;
    float val = 0.f;
    if (shi >= 0 && shi < SG && swj >= 0 && swj < SG && r >= 0 && r < HP &&
        c >= 0 && c < WP)
      val = sims[((size_t)(r * WP + c)) * (SG * SG) + shi * SG + swj];
    smpi[loc * PSTR + s] = val;
  }
  __syncthreads();

  const int head = tid & 3;
  const int pl = tid >> 2;
  const int py = pl >> 3, px = pl & 7;
  const int h = th * 8 + py, w = tw * 8 + px;
  const int pix = h * WP + w;
  int hs = h - 3;
  hs = hs < 0 ? 0 : (hs > HP - 7 ? HP - 7 : hs);
  int wsb = w - 3;
  wsb = wsb < 0 ? 0 : (wsb > WP - 7 ? WP - 7 : wsb);
  const int rl0 = hs - rowBase;   // 0..7
  const int cl0 = wsb - colBase;  // 0..7
  const int hq = head << 4;       // head channel base

  const float4* qp = (const float4*)(qb + (size_t)pix * 64 + hq);
  const float4 q0 = qp[0], q1 = qp[1], q2 = qp[2], q3 = qp[3];

// accumulate bf16 pair u into t against q-pair (qa=even ch, qb=odd ch)
#define ACC2(u, qa, qb)                              \
  t = fmaf(__uint_as_float((u) << 16), (qa), t);     \
  t = fmaf(__uint_as_float((u) & 0xFFFF0000u), (qb), t);

  // ---- pass 1: logits -> exp -> S, D9 ----
  float D9[9];
#pragma unroll
  for (int s = 0; s < 9; ++s) D9[s] = 0.f;
  float S = 0.f;
#pragma unroll 1
  for (int kh = 0; kh < 7; ++kh) {
    const int rbase = (rl0 + kh) * 14 + cl0;
    const unsigned short* kr = smK + rbase * KSTRU + hq;
    const float* pr = smpi + rbase * PSTR;
#pragma unroll
    for (int kw = 0; kw < 7; ++kw) {
      const unsigned short* kp = kr + kw * KSTRU;
      const uint4 ka = *(const uint4*)kp;        // ch 0..7
      const uint4 kb8 = *(const uint4*)(kp + 8); // ch 8..15
      float t = 0.f;
      ACC2(ka.x, q0.x, q0.y)
      ACC2(ka.y, q0.z, q0.w)
      ACC2(ka.z, q1.x, q1.y)
      ACC2(ka.w, q1.z, q1.w)
      ACC2(kb8.x, q2.x, q2.y)
      ACC2(kb8.y, q2.z, q2.w)
      ACC2(kb8.z, q3.x, q3.y)
      ACC2(kb8.w, q3.z, q3.w)
      const float e = __expf(t);
      S += e;
      const float* pp = pr + kw * PSTR;
      const float4 p0 = *(const float4*)pp;
      const float4 p1 = *(const float4*)(pp + 4);
      const float p8 = pp[8];
      D9[0] = fmaf(e, p0.x, D9[0]);
      D9[1] = fmaf(e, p0.y, D9[1]);
      D9[2] = fmaf(e, p0.z, D9[2]);
      D9[3] = fmaf(e, p0.w, D9[3]);
      D9[4] = fmaf(e, p1.x, D9[4]);
      D9[5] = fmaf(e, p1.y, D9[5]);
      D9[6] = fmaf(e, p1.z, D9[6]);
      D9[7] = fmaf(e, p1.w, D9[7]);
      D9[8] = fmaf(e, p8, D9[8]);
    }
  }

  // ---- coef_s = ws[s] / (D[s] + 1e-10*S) ----
  float coef[9];
  {
    const float* pp = smpi + ((h - rowBase) * 14 + (w - colBase)) * PSTR;
    const float4 p0 = *(const float4*)pp;
    const float4 p1 = *(const float4*)(pp + 4);
    const float p8 = pp[8];
    const float epsS = 1e-10f * S;
    coef[0] = p0.x / (D9[0] + epsS);
    coef[1] = p0.y / (D9[1] + epsS);
    coef[2] = p0.z / (D9[2] + epsS);
    coef[3] = p0.w / (D9[3] + epsS);
    coef[4] = p1.x / (D9[4] + epsS);
    coef[5] = p1.y / (D9[5] + epsS);
    coef[6] = p1.z / (D9[6] + epsS);
    coef[7] = p1.w / (D9[7] + epsS);
    coef[8] = p8 / (D9[8] + epsS);
  }

  // ---- pass 2: recompute e; a2 = e * (coef . pi); o += a2 * v ----
  float4 o0 = make_float4(0.f, 0.f, 0.f, 0.f);
  float4 o1 = make_float4(0.f, 0.f, 0.f, 0.f);
  float4 o2 = make_float4(0.f, 0.f, 0.f, 0.f);
  float4 o3 = make_float4(0.f, 0.f, 0.f, 0.f);
#pragma unroll 1
  for (int kh = 0; kh < 7; ++kh) {
    const int rbase = (rl0 + kh) * 14 + cl0;
    const unsigned short* kr = smK + rbase * KSTRU + hq;
    const unsigned short* vr = smV + rbase * KSTRU + hq;
    const float* pr = smpi + rbase * PSTR;
#pragma unroll
    for (int kw = 0; kw < 7; ++kw) {
      const unsigned short* kp = kr + kw * KSTRU;
      const uint4 ka = *(const uint4*)kp;
      const uint4 kb8 = *(const uint4*)(kp + 8);
      float t = 0.f;
      ACC2(ka.x, q0.x, q0.y)
      ACC2(ka.y, q0.z, q0.w)
      ACC2(ka.z, q1.x, q1.y)
      ACC2(ka.w, q1.z, q1.w)
      ACC2(kb8.x, q2.x, q2.y)
      ACC2(kb8.y, q2.z, q2.w)
      ACC2(kb8.z, q3.x, q3.y)
      ACC2(kb8.w, q3.z, q3.w)
      const float e = __expf(t);
      const float* pp = pr + kw * PSTR;
      const float4 p0 = *(const float4*)pp;
      const float4 p1 = *(const float4*)(pp + 4);
      const float p8 = pp[8];
      float tc = coef[0] * p0.x + coef[1] * p0.y + coef[2] * p0.z +
                 coef[3] * p0.w + coef[4] * p1.x + coef[5] * p1.y +
                 coef[6] * p1.z + coef[7] * p1.w + coef[8] * p8;
      const float a2 = e * tc;
      const unsigned short* vp = vr + kw * KSTRU;
      const uint4 va = *(const uint4*)vp;
      const uint4 vb8 = *(const uint4*)(vp + 8);
      o0.x = fmaf(a2, __uint_as_float(va.x << 16), o0.x);
      o0.y = fmaf(a2, __uint_as_float(va.x & 0xFFFF0000u), o0.y);
      o0.z = fmaf(a2, __uint_as_float(va.y << 16), o0.z);
      o0.w = fmaf(a2, __uint_as_float(va.y & 0xFFFF0000u), o0.w);
      o1.x = fmaf(a2, __uint_as_float(va.z << 16), o1.x);
      o1.y = fmaf(a2, __uint_as_float(va.z & 0xFFFF0000u), o1.y);
      o1.z = fmaf(a2, __uint_as_float(va.w << 16), o1.z);
      o1.w = fmaf(a2, __uint_as_float(va.w & 0xFFFF0000u), o1.w);
      o2.x = fmaf(a2, __uint_as_float(vb8.x << 16), o2.x);
      o2.y = fmaf(a2, __uint_as_float(vb8.x & 0xFFFF0000u), o2.y);
      o2.z = fmaf(a2, __uint_as_float(vb8.y << 16), o2.z);
      o2.w = fmaf(a2, __uint_as_float(vb8.y & 0xFFFF0000u), o2.w);
      o3.x = fmaf(a2, __uint_as_float(vb8.z << 16), o3.x);
      o3.y = fmaf(a2, __uint_as_float(vb8.z & 0xFFFF0000u), o3.y);
      o3.z = fmaf(a2, __uint_as_float(vb8.w << 16), o3.z);
      o3.w = fmaf(a2, __uint_as_float(vb8.w & 0xFFFF0000u), o3.w);
    }
  }
#undef ACC2
  float4* op = (float4*)(pre + (size_t)pix * 64 + hq);
  op[0] = o0;
  op[1] = o1;
  op[2] = o2;
  op[3] = o3;
}

// ---------------- Kernel 3: output projection --------------------------------
__global__ __launch_bounds__(256) void proj_kernel(
    const float* __restrict__ pre, const float* __restrict__ w_proj,
    float* __restrict__ out) {
  const int jb = blockIdx.y;  // 0..1
  const int pix = blockIdx.x * 256 + threadIdx.x;
  float xv[64];
  const float4* pp = (const float4*)(pre + (size_t)pix * 64);
#pragma unroll
  for (int i = 0; i < 16; ++i) {
    const float4 t = pp[i];
    xv[i * 4 + 0] = t.x;
    xv[i * 4 + 1] = t.y;
    xv[i * 4 + 2] = t.z;
    xv[i * 4 + 3] = t.w;
  }
  float acc[32];
#pragma unroll
  for (int j = 0; j < 32; ++j) acc[j] = 0.f;
  const int j0 = jb * 32;
#pragma unroll
  for (int c = 0; c < 64; ++c) {
    const float* wr = w_proj + c * 64 + j0;
    const float xc = xv[c];
#pragma unroll
    for (int j = 0; j < 32; ++j) acc[j] = fmaf(xc, wr[j], acc[j]);
  }
#pragma unroll
  for (int j = 0; j < 32; ++j) out[(size_t)(j0 + j) * NPIX + pix] = acc[j];
}

extern "C" void kernel_launch(void* const* d_in, const int* in_sizes, int n_in,
                              void* d_out, int out_size, void* d_ws,
                              size_t ws_size, hipStream_t stream) {
  const float* x = (const float*)d_in[0];
  const float* sims = (const float*)d_in[1];
  const float* w_qk = (const float*)d_in[2];
  const float* w_v = (const float*)d_in[3];
  const float* w_proj = (const float*)d_in[4];
  float* out = (float*)d_out;

  float* qb = (float*)d_ws;
  float* kb = qb + (size_t)NPIX * 64;
  float* vb = kb + (size_t)NPIX * 64;
  float* pre = vb + (size_t)NPIX * 64;

  qkv_kernel<<<dim3(144, 6), 256, 0, stream>>>(x, w_qk, w_v, qb, kb, vb);
  attn_kernel<<<dim3(576), 256, 0, stream>>>(qb, kb, vb, sims, pre);
  proj_kernel<<<dim3(144, 2), 256, 0, stream>>>(pre, w_proj, out);
}

// Round 6
// 100.745 us; speedup vs baseline: 6.7704x; 1.2293x over previous
//
#include <hip/hip_runtime.h>

#define HP 192
#define WP 192
#define NPIX (HP * WP)   // 36864
#define SG 24
#define KSTRU 72         // smK row stride in ushorts: 144 B (9x16B, odd) 
#define PSTR 12          // smpi row stride (floats)

__device__ __forceinline__ unsigned int bfpack(float a, float b) {
  unsigned int ua = __float_as_uint(a), ub = __float_as_uint(b);
  ua = (ua + 0x7FFFu + ((ua >> 16) & 1u)) >> 16;   // RTNE bf16
  ub = (ub + 0x7FFFu + ((ub >> 16) & 1u)) >> 16;
  return ua | (ub << 16);
}

// ---------------- Kernel 1: QKV projection -----------------------------------
// grid (144, 12): jb picks 16 output columns of [q|k|v]; 1728 blocks total for
// latency hiding (6.75 waves/SIMD). x re-reads are L2-resident (9.4 MB).
__global__ __launch_bounds__(256) void qkv_kernel(
    const float* __restrict__ x,
    const float* __restrict__ w_qk,
    const float* __restrict__ w_v,
    float* __restrict__ qb, float* __restrict__ kb, float* __restrict__ vb) {
  const int jb = blockIdx.y;  // 0..11
  const int pix = blockIdx.x * 256 + threadIdx.x;
  float xv[64];
#pragma unroll
  for (int c = 0; c < 64; ++c) xv[c] = x[c * NPIX + pix];
  float acc[16];
#pragma unroll
  for (int j = 0; j < 16; ++j) acc[j] = 0.f;
  const int j0 = jb * 16;
  if (jb < 8) {
#pragma unroll
    for (int c = 0; c < 64; ++c) {
      const float* wr = w_qk + c * 128 + j0;
      const float xc = xv[c];
#pragma unroll
      for (int j = 0; j < 16; ++j) acc[j] = fmaf(xc, wr[j], acc[j]);
    }
  } else {
#pragma unroll
    for (int c = 0; c < 64; ++c) {
      const float* wr = w_v + c * 64 + (j0 - 128);
      const float xc = xv[c];
#pragma unroll
      for (int j = 0; j < 16; ++j) acc[j] = fmaf(xc, wr[j], acc[j]);
    }
  }
  float* dst;
  float mul = 1.0f;
  if (jb < 4) {
    dst = qb + (size_t)pix * 64 + j0;
    mul = 0.25f;  // hd^-0.5, hd=16
  } else if (jb < 8) {
    dst = kb + (size_t)pix * 64 + (j0 - 64);
  } else {
    dst = vb + (size_t)pix * 64 + (j0 - 128);
  }
#pragma unroll
  for (int j = 0; j < 16; ++j) dst[j] = acc[j] * mul;
}

// ---------------- Kernel 2: attention ----------------------------------------
// Block = 8x8 pixel tile, 256 threads = 64 px x 4 heads.
// K staged in LDS as bf16 (28.2 KB) + pi f32 (9.4 KB) = 37.6 KB -> 4 blocks/CU
// (16 waves/CU). V read directly from global (once per neighbor; L1/L2 hot).
// No per-thread a[49]: pass 2 recomputes exp from the same LDS bf16 K.
// Dot products tree-reduced (4 partial chains) to cut dependent latency.
__global__ __launch_bounds__(256) void attn_kernel(
    const float* __restrict__ qb, const float* __restrict__ kb,
    const float* __restrict__ vb, const float* __restrict__ sims,
    float* __restrict__ pre) {
  __shared__ __align__(16) unsigned short smK[196 * KSTRU];
  __shared__ __align__(16) float smpi[196 * PSTR];
  const int tile = blockIdx.x;
  const int th = tile / 24, tw = tile % 24;
  const int rowBase = th * 8 - 3, colBase = tw * 8 - 3;
  const int tid = threadIdx.x;

  // ---- stage K tile: global f32 -> bf16 LDS (8-ch chunks) ----
  for (int i = tid; i < 196 * 8; i += 256) {
    const int loc = i >> 3, d8 = i & 7;
    const int rl = loc / 14, cl = loc - rl * 14;
    const int r = rowBase + rl, c = colBase + cl;
    uint4 kw4 = make_uint4(0u, 0u, 0u, 0u);
    if (r >= 0 && r < HP && c >= 0 && c < WP) {
      const size_t base = ((size_t)(r * WP + c)) * 64 + (d8 << 3);
      const float4 ka = *(const float4*)(kb + base);
      const float4 kb8 = *(const float4*)(kb + base + 4);
      kw4.x = bfpack(ka.x, ka.y);
      kw4.y = bfpack(ka.z, ka.w);
      kw4.z = bfpack(kb8.x, kb8.y);
      kw4.w = bfpack(kb8.z, kb8.w);
    }
    *(uint4*)(smK + loc * KSTRU + (d8 << 3)) = kw4;
  }
  // ---- stage pi table: 196 locations x 9 block-uniform labels (f32) ----
  for (int i = tid; i < 196 * 9; i += 256) {
    const int loc = i / 9, s = i - loc * 9;
    const int rl = loc / 14, cl = loc - rl * 14;
    const int r = rowBase + rl, c = colBase + cl;
    const int dh = s / 3, dw = s - dh * 3;
    const int shi = th + dh - 1, swj = tw + dw - 1;
    float val = 0.f;
    if (shi >= 0 && shi < SG && swj >= 0 && swj < SG && r >= 0 && r < HP &&
        c >= 0 && c < WP)
      val = sims[((size_t)(r * WP + c)) * (SG * SG) + shi * SG + swj];
    smpi[loc * PSTR + s] = val;
  }
  __syncthreads();

  const int head = tid & 3;
  const int pl = tid >> 2;
  const int py = pl >> 3, px = pl & 7;
  const int h = th * 8 + py, w = tw * 8 + px;
  const int pix = h * WP + w;
  int hs = h - 3;
  hs = hs < 0 ? 0 : (hs > HP - 7 ? HP - 7 : hs);
  int wsb = w - 3;
  wsb = wsb < 0 ? 0 : (wsb > WP - 7 ? WP - 7 : wsb);
  const int rl0 = hs - rowBase;   // 0..7
  const int cl0 = wsb - colBase;  // 0..7
  const int hq = head << 4;       // head channel base

  const float4* qp = (const float4*)(qb + (size_t)pix * 64 + hq);
  const float4 q0 = qp[0], q1 = qp[1], q2 = qp[2], q3 = qp[3];

// bf16 pair u against q-pair, accumulating into tn (tree partial)
#define ACC2T(tn, u, qa, qb)                            \
  tn = fmaf(__uint_as_float((u) << 16), (qa), tn);      \
  tn = fmaf(__uint_as_float((u) & 0xFFFF0000u), (qb), tn);

// full 16-ch dot of LDS bf16 row kp vs q, tree-reduced into t
#define DOT16(t, kp)                                    \
  {                                                     \
    const uint4 ka = *(const uint4*)(kp);               \
    const uint4 kc = *(const uint4*)((kp) + 8);         \
    float t0 = 0.f, t1 = 0.f, t2 = 0.f, t3 = 0.f;       \
    ACC2T(t0, ka.x, q0.x, q0.y)                         \
    ACC2T(t0, ka.y, q0.z, q0.w)                         \
    ACC2T(t1, ka.z, q1.x, q1.y)                         \
    ACC2T(t1, ka.w, q1.z, q1.w)                         \
    ACC2T(t2, kc.x, q2.x, q2.y)                         \
    ACC2T(t2, kc.y, q2.z, q2.w)                         \
    ACC2T(t3, kc.z, q3.x, q3.y)                         \
    ACC2T(t3, kc.w, q3.z, q3.w)                         \
    t = (t0 + t1) + (t2 + t3);                          \
  }

  // ---- pass 1: logits -> exp -> S, D9 ----
  float D9[9];
#pragma unroll
  for (int s = 0; s < 9; ++s) D9[s] = 0.f;
  float S = 0.f;
#pragma unroll 1
  for (int kh = 0; kh < 7; ++kh) {
    const int rbase = (rl0 + kh) * 14 + cl0;
    const unsigned short* kr = smK + rbase * KSTRU + hq;
    const float* pr = smpi + rbase * PSTR;
#pragma unroll
    for (int kw = 0; kw < 7; ++kw) {
      float t;
      DOT16(t, kr + kw * KSTRU)
      const float e = __expf(t);
      S += e;
      const float* pp = pr + kw * PSTR;
      const float4 p0 = *(const float4*)pp;
      const float4 p1 = *(const float4*)(pp + 4);
      const float p8 = pp[8];
      D9[0] = fmaf(e, p0.x, D9[0]);
      D9[1] = fmaf(e, p0.y, D9[1]);
      D9[2] = fmaf(e, p0.z, D9[2]);
      D9[3] = fmaf(e, p0.w, D9[3]);
      D9[4] = fmaf(e, p1.x, D9[4]);
      D9[5] = fmaf(e, p1.y, D9[5]);
      D9[6] = fmaf(e, p1.z, D9[6]);
      D9[7] = fmaf(e, p1.w, D9[7]);
      D9[8] = fmaf(e, p8, D9[8]);
    }
  }

  // ---- coef_s = ws[s] / (D[s] + 1e-10*S) ----
  float coef[9];
  {
    const float* pp = smpi + ((h - rowBase) * 14 + (w - colBase)) * PSTR;
    const float4 p0 = *(const float4*)pp;
    const float4 p1 = *(const float4*)(pp + 4);
    const float p8 = pp[8];
    const float epsS = 1e-10f * S;
    coef[0] = p0.x / (D9[0] + epsS);
    coef[1] = p0.y / (D9[1] + epsS);
    coef[2] = p0.z / (D9[2] + epsS);
    coef[3] = p0.w / (D9[3] + epsS);
    coef[4] = p1.x / (D9[4] + epsS);
    coef[5] = p1.y / (D9[5] + epsS);
    coef[6] = p1.z / (D9[6] + epsS);
    coef[7] = p1.w / (D9[7] + epsS);
    coef[8] = p8 / (D9[8] + epsS);
  }

  // ---- pass 2: recompute e; a2 = e * (coef . pi); o += a2 * v(global) ----
  float4 o0 = make_float4(0.f, 0.f, 0.f, 0.f);
  float4 o1 = make_float4(0.f, 0.f, 0.f, 0.f);
  float4 o2 = make_float4(0.f, 0.f, 0.f, 0.f);
  float4 o3 = make_float4(0.f, 0.f, 0.f, 0.f);
#pragma unroll 1
  for (int kh = 0; kh < 7; ++kh) {
    const int rbase = (rl0 + kh) * 14 + cl0;
    const unsigned short* kr = smK + rbase * KSTRU + hq;
    const float* pr = smpi + rbase * PSTR;
    const float* vrow = vb + (size_t)((hs + kh) * WP + wsb) * 64 + hq;
#pragma unroll
    for (int kw = 0; kw < 7; ++kw) {
      float t;
      DOT16(t, kr + kw * KSTRU)
      const float e = __expf(t);
      const float* pp = pr + kw * PSTR;
      const float4 p0 = *(const float4*)pp;
      const float4 p1 = *(const float4*)(pp + 4);
      const float p8 = pp[8];
      const float tca = coef[0] * p0.x + coef[1] * p0.y;
      const float tcb = coef[2] * p0.z + coef[3] * p0.w;
      const float tcc = coef[4] * p1.x + coef[5] * p1.y;
      const float tcd = coef[6] * p1.z + coef[7] * p1.w;
      const float tc = ((tca + tcb) + (tcc + tcd)) + coef[8] * p8;
      const float a2 = e * tc;
      const float* vp = vrow + kw * 64;
      const float4 v0 = *(const float4*)(vp);
      const float4 v1 = *(const float4*)(vp + 4);
      const float4 v2 = *(const float4*)(vp + 8);
      const float4 v3 = *(const float4*)(vp + 12);
      o0.x = fmaf(a2, v0.x, o0.x);
      o0.y = fmaf(a2, v0.y, o0.y);
      o0.z = fmaf(a2, v0.z, o0.z);
      o0.w = fmaf(a2, v0.w, o0.w);
      o1.x = fmaf(a2, v1.x, o1.x);
      o1.y = fmaf(a2, v1.y, o1.y);
      o1.z = fmaf(a2, v1.z, o1.z);
      o1.w = fmaf(a2, v1.w, o1.w);
      o2.x = fmaf(a2, v2.x, o2.x);
      o2.y = fmaf(a2, v2.y, o2.y);
      o2.z = fmaf(a2, v2.z, o2.z);
      o2.w = fmaf(a2, v2.w, o2.w);
      o3.x = fmaf(a2, v3.x, o3.x);
      o3.y = fmaf(a2, v3.y, o3.y);
      o3.z = fmaf(a2, v3.z, o3.z);
      o3.w = fmaf(a2, v3.w, o3.w);
    }
  }
#undef DOT16
#undef ACC2T
  float4* op = (float4*)(pre + (size_t)pix * 64 + hq);
  op[0] = o0;
  op[1] = o1;
  op[2] = o2;
  op[3] = o3;
}

// ---------------- Kernel 3: output projection --------------------------------
// grid (144, 4): jb picks 16 output channels; 576 blocks.
__global__ __launch_bounds__(256) void proj_kernel(
    const float* __restrict__ pre, const float* __restrict__ w_proj,
    float* __restrict__ out) {
  const int jb = blockIdx.y;  // 0..3
  const int pix = blockIdx.x * 256 + threadIdx.x;
  float xv[64];
  const float4* pp = (const float4*)(pre + (size_t)pix * 64);
#pragma unroll
  for (int i = 0; i < 16; ++i) {
    const float4 t = pp[i];
    xv[i * 4 + 0] = t.x;
    xv[i * 4 + 1] = t.y;
    xv[i * 4 + 2] = t.z;
    xv[i * 4 + 3] = t.w;
  }
  float acc[16];
#pragma unroll
  for (int j = 0; j < 16; ++j) acc[j] = 0.f;
  const int j0 = jb * 16;
#pragma unroll
  for (int c = 0; c < 64; ++c) {
    const float* wr = w_proj + c * 64 + j0;
    const float xc = xv[c];
#pragma unroll
    for (int j = 0; j < 16; ++j) acc[j] = fmaf(xc, wr[j], acc[j]);
  }
#pragma unroll
  for (int j = 0; j < 16; ++j) out[(size_t)(j0 + j) * NPIX + pix] = acc[j];
}

extern "C" void kernel_launch(void* const* d_in, const int* in_sizes, int n_in,
                              void* d_out, int out_size, void* d_ws,
                              size_t ws_size, hipStream_t stream) {
  const float* x = (const float*)d_in[0];
  const float* sims = (const float*)d_in[1];
  const float* w_qk = (const float*)d_in[2];
  const float* w_v = (const float*)d_in[3];
  const float* w_proj = (const float*)d_in[4];
  float* out = (float*)d_out;

  float* qb = (float*)d_ws;
  float* kb = qb + (size_t)NPIX * 64;
  float* vb = kb + (size_t)NPIX * 64;
  float* pre = vb + (size_t)NPIX * 64;

  qkv_kernel<<<dim3(144, 12), 256, 0, stream>>>(x, w_qk, w_v, qb, kb, vb);
  attn_kernel<<<dim3(576), 256, 0, stream>>>(qb, kb, vb, sims, pre);
  proj_kernel<<<dim3(144, 4), 256, 0, stream>>>(pre, w_proj, out);
}